// Round 15
// baseline (2649.283 us; speedup 1.0000x reference)
//
#include <hip/hip_runtime.h>
#include <hip/hip_cooperative_groups.h>
#include <hip/hip_bf16.h>
#include <math.h>

namespace cg = cooperative_groups;

#define N_NODES 50000
#define N_EDGES 800000
#define IN_FEAT 32
#define EDGE_FEAT 8
#define HEADS 3
#define N_GRAPHS 64
#define NBLK_SCAN 196   // ceil(50000/256)

typedef __hip_bfloat16 bf16;

static __device__ __forceinline__ float fast_sigmoid(float x){
    return __builtin_amdgcn_rcpf(1.f + __expf(-x));
}
static __device__ __forceinline__ float fast_softplus(float x){
    return fmaxf(x, 0.f) + __logf(1.f + __expf(-fabsf(x)));
}
static __device__ __forceinline__ float lrelu02(float x){ return x > 0.f ? x : 0.2f*x; }
static __device__ __forceinline__ float b2f(bf16 h){ return __bfloat162float(h); }

// =================== shared phase bodies ===================
union MegaLDS {
    float sC[32*128];                       // 16 KB  (CGConv weights)
    float sW[96*48];                        // 18.4 KB (GAT linear weights; also holds 32*96)
    int   scan[256];
    struct { float p[3][260]; float red[12]; float sred[3]; } f2;   // fused GAT (+pad 260 -> no bank conflict)
    struct { int range[2]; float red[240]; float gm[48]; float g1[16]; } pm;
};

__device__ void load_sC(float* sC, const float* Wf, const float* Ws){
    for (int i = threadIdx.x; i < 32*128; i += 256){
        int k = i >> 7, j = i & 127;
        float w;
        if      (j < 32)  w = Wf[k*32 + j];             // AF
        else if (j < 64)  w = Ws[k*32 + (j-32)];        // AS
        else if (j < 96)  w = Wf[(32+k)*32 + (j-64)];   // BF
        else              w = Ws[(32+k)*32 + (j-96)];   // BS
        sC[i] = w;
    }
}

__device__ void pre_phase(const float* __restrict__ x, const float* __restrict__ bfv,
                          const float* __restrict__ bsv, const float* __restrict__ sC,
                          bf16* __restrict__ AB, int gid, int gsz){
    for (int idx = gid; idx < N_NODES*128; idx += gsz){
        int n = idx >> 7, j = idx & 127;
        float a = 0.f;
        if (j < 32) a = bfv[j];
        else if (j < 64) a = bsv[j-32];
        const float4* xr = (const float4*)(x + (size_t)n*32);
        #pragma unroll
        for (int k4 = 0; k4 < 8; k4++){
            float4 v = xr[k4];
            int k = k4*4;
            a = fmaf(v.x, sC[(k  )*128 + j], a);
            a = fmaf(v.y, sC[(k+1)*128 + j], a);
            a = fmaf(v.z, sC[(k+2)*128 + j], a);
            a = fmaf(v.w, sC[(k+3)*128 + j], a);
        }
        AB[idx] = __float2bfloat16(a);
    }
}

__device__ void gather_phase(const float* __restrict__ xin, const bf16* __restrict__ AB,
    const float* __restrict__ ea, const int* __restrict__ rowptr,
    const int* __restrict__ esrc, const int* __restrict__ eord,
    const float* __restrict__ Wf, const float* __restrict__ Ws,
    float* __restrict__ outp, int gwid, int gnw){
    const int lane = threadIdx.x & 63;
    const int half = lane >> 5, c = lane & 31;
    const float* WzOwn  = half ? Ws : Wf;
    const float* WzSwap = half ? Wf : Ws;
    float wo[8], wx[8];
    #pragma unroll
    for (int k = 0; k < 8; k++){
        wo[k] = WzOwn[(64+k)*32+c];
        wx[k] = WzSwap[(64+k)*32+c];
    }
    const int offOwn  = 64 + half*32 + c;
    const int offSwap = 96 - half*32 + c;
    for (int d0 = gwid; d0 < N_NODES; d0 += gnw){
        const int d = __builtin_amdgcn_readfirstlane(d0);
        const int lo = rowptr[d], hi = rowptr[d+1];
        const float baseOwn  = b2f(AB[d*128 + half*32 + c]);
        const float baseSwap = b2f(AB[d*128 + (32 - half*32) + c]);
        float acc = 0.f;
        auto mv = [&](float v, const float* w8, const float4& e0, const float4& e1) -> float {
            v = fmaf(e0.x, w8[0], v); v = fmaf(e0.y, w8[1], v);
            v = fmaf(e0.z, w8[2], v); v = fmaf(e0.w, w8[3], v);
            v = fmaf(e1.x, w8[4], v); v = fmaf(e1.y, w8[5], v);
            v = fmaf(e1.z, w8[6], v); v = fmaf(e1.w, w8[7], v);
            return v;
        };
        auto pair = [&](int i) -> float {
            int sA = __builtin_amdgcn_readfirstlane(esrc[i]);
            int sB = __builtin_amdgcn_readfirstlane(esrc[i+1]);
            int eA = __builtin_amdgcn_readfirstlane(eord[i]);
            int eB = __builtin_amdgcn_readfirstlane(eord[i+1]);
            float bA = b2f(AB[sA*128 + offOwn]);
            float bB = b2f(AB[sB*128 + offSwap]);
            const float4* epA = (const float4*)(ea + (size_t)eA*8);
            const float4* epB = (const float4*)(ea + (size_t)eB*8);
            float4 ea0 = epA[0], ea1 = epA[1];
            float4 ea2 = epB[0], ea3 = epB[1];
            float vA = mv(baseOwn  + bA, wo, ea0, ea1);
            float vB = mv(baseSwap + bB, wx, ea2, ea3);
            float xA = __shfl_xor(vA, 32, 64);
            float xB = __shfl_xor(vB, 32, 64);
            float fv = half ? vB : vA;
            float sv = half ? xB : xA;
            return fast_sigmoid(fv) * fast_softplus(sv);
        };
        int i = lo;
        for (; i + 7 < hi; i += 8){
            acc += pair(i);   acc += pair(i+2);
            acc += pair(i+4); acc += pair(i+6);
        }
        for (; i + 1 < hi; i += 2) acc += pair(i);
        for (; i < hi; i++){
            int s = __builtin_amdgcn_readfirstlane(esrc[i]);
            int e = __builtin_amdgcn_readfirstlane(eord[i]);
            float b = b2f(AB[s*128 + offOwn]);
            const float4* ep = (const float4*)(ea + (size_t)e*8);
            float4 ea0 = ep[0], ea1 = ep[1];
            float v = mv(baseOwn + b, wo, ea0, ea1);
            float o = __shfl_xor(v, 32, 64);
            if (half == 0) acc += fast_sigmoid(v) * fast_softplus(o);
        }
        float total = acc + __shfl_xor(acc, 32, 64);
        if (half == 0) outp[d*32 + c] = fmaxf(xin[d*32 + c] + total, 0.f);
    }
}

template<int Ci, int Co, int C>
__device__ void linear_al_phase(const float* __restrict__ in, const float* __restrict__ sW,
    const float* __restrict__ a_src, const float* __restrict__ a_dst,
    bf16* __restrict__ out, float* __restrict__ als, float* __restrict__ ald,
    int gid, int gsz){
    // flat (node,co) grid-stride; 64-lane waves always contain C-aligned head groups
    for (int idx = gid; idx < N_NODES*Co; idx += gsz){
        int n = idx / Co, co = idx - n*Co;
        const float* row = in + (size_t)n*Ci;
        float a = 0.f;
        #pragma unroll
        for (int k = 0; k < Ci; k++) a = fmaf(row[k], sW[k*Co + co], a);
        out[(size_t)n*Co + co] = __float2bfloat16(a);
        float s1 = a*a_src[co], s2 = a*a_dst[co];
        #pragma unroll
        for (int off = C/2; off; off >>= 1){
            s1 += __shfl_xor(s1, off, 64);
            s2 += __shfl_xor(s2, off, 64);
        }
        if ((co & (C-1)) == 0){
            als[n*HEADS + co/C] = s1;
            ald[n*HEADS + co/C] = s2;
        }
    }
}

template<int C>
__device__ void fused2_phase(const bf16* __restrict__ hg, const int* __restrict__ rowptr,
    const int* __restrict__ esrc, const float* __restrict__ als, const float* __restrict__ ald,
    const float* __restrict__ bias, float* __restrict__ O, MegaLDS* L){
    const int HC = HEADS*C;
    const int tid = threadIdx.x;
    for (int d = blockIdx.x; d < N_NODES; d += gridDim.x){
        const int lo = rowptr[d], hi = rowptr[d+1];
        const float ad0 = ald[d*3+0], ad1 = ald[d*3+1], ad2 = ald[d*3+2];
        const int h = (tid < HC) ? tid / C : 0;
        float acc = 0.f, ps0 = 0.f, ps1 = 0.f, ps2 = 0.f;
        for (int base = lo; base < hi; base += 256){
            const int cnt = min(256, hi - base);
            if (tid < cnt){
                int s = esrc[base + tid];
                float p0 = __expf(lrelu02(als[s*3+0] + ad0));
                float p1 = __expf(lrelu02(als[s*3+1] + ad1));
                float p2 = __expf(lrelu02(als[s*3+2] + ad2));
                L->f2.p[0][tid] = p0; L->f2.p[1][tid] = p1; L->f2.p[2][tid] = p2;
                ps0 += p0; ps1 += p1; ps2 += p2;
            }
            __syncthreads();
            if (tid < HC){
                const float* ph = &L->f2.p[h][0];
                int j = 0;
                for (; j + 7 < cnt; j += 8){
                    int i = base + j;
                    int s0 = __builtin_amdgcn_readfirstlane(esrc[i]);
                    int s1 = __builtin_amdgcn_readfirstlane(esrc[i+1]);
                    int s2 = __builtin_amdgcn_readfirstlane(esrc[i+2]);
                    int s3 = __builtin_amdgcn_readfirstlane(esrc[i+3]);
                    int s4 = __builtin_amdgcn_readfirstlane(esrc[i+4]);
                    int s5 = __builtin_amdgcn_readfirstlane(esrc[i+5]);
                    int s6 = __builtin_amdgcn_readfirstlane(esrc[i+6]);
                    int s7 = __builtin_amdgcn_readfirstlane(esrc[i+7]);
                    float g0 = b2f(hg[(size_t)s0*HC + tid]);
                    float g1 = b2f(hg[(size_t)s1*HC + tid]);
                    float g2 = b2f(hg[(size_t)s2*HC + tid]);
                    float g3 = b2f(hg[(size_t)s3*HC + tid]);
                    float g4 = b2f(hg[(size_t)s4*HC + tid]);
                    float g5 = b2f(hg[(size_t)s5*HC + tid]);
                    float g6 = b2f(hg[(size_t)s6*HC + tid]);
                    float g7 = b2f(hg[(size_t)s7*HC + tid]);
                    acc = fmaf(ph[j],   g0, acc); acc = fmaf(ph[j+1], g1, acc);
                    acc = fmaf(ph[j+2], g2, acc); acc = fmaf(ph[j+3], g3, acc);
                    acc = fmaf(ph[j+4], g4, acc); acc = fmaf(ph[j+5], g5, acc);
                    acc = fmaf(ph[j+6], g6, acc); acc = fmaf(ph[j+7], g7, acc);
                }
                for (; j + 3 < cnt; j += 4){
                    int i = base + j;
                    int s0 = __builtin_amdgcn_readfirstlane(esrc[i]);
                    int s1 = __builtin_amdgcn_readfirstlane(esrc[i+1]);
                    int s2 = __builtin_amdgcn_readfirstlane(esrc[i+2]);
                    int s3 = __builtin_amdgcn_readfirstlane(esrc[i+3]);
                    float g0 = b2f(hg[(size_t)s0*HC + tid]);
                    float g1 = b2f(hg[(size_t)s1*HC + tid]);
                    float g2 = b2f(hg[(size_t)s2*HC + tid]);
                    float g3 = b2f(hg[(size_t)s3*HC + tid]);
                    acc = fmaf(ph[j],   g0, acc); acc = fmaf(ph[j+1], g1, acc);
                    acc = fmaf(ph[j+2], g2, acc); acc = fmaf(ph[j+3], g3, acc);
                }
                for (; j < cnt; j++){
                    int s = __builtin_amdgcn_readfirstlane(esrc[base + j]);
                    acc = fmaf(ph[j], b2f(hg[(size_t)s*HC + tid]), acc);
                }
            }
            __syncthreads();
        }
        #pragma unroll
        for (int off = 32; off; off >>= 1){
            ps0 += __shfl_xor(ps0, off, 64);
            ps1 += __shfl_xor(ps1, off, 64);
            ps2 += __shfl_xor(ps2, off, 64);
        }
        if ((tid & 63) == 0){
            int wv = tid >> 6;
            L->f2.red[wv*3+0] = ps0; L->f2.red[wv*3+1] = ps1; L->f2.red[wv*3+2] = ps2;
        }
        __syncthreads();
        if (tid == 0){
            L->f2.sred[0] = L->f2.red[0]+L->f2.red[3]+L->f2.red[6]+L->f2.red[9];
            L->f2.sred[1] = L->f2.red[1]+L->f2.red[4]+L->f2.red[7]+L->f2.red[10];
            L->f2.sred[2] = L->f2.red[2]+L->f2.red[5]+L->f2.red[8]+L->f2.red[11];
        }
        __syncthreads();
        if (tid < HC){
            float slh = lrelu02(als[d*3+h] + ald[d*3+h]);
            float p_self = __expf(slh);
            float r = __builtin_amdgcn_rcpf(L->f2.sred[h] + p_self + 1e-16f);
            float self_hg = b2f(hg[(size_t)d*HC + tid]);
            O[(size_t)d*HC + tid] = fmaxf(fmaf(acc + p_self*self_hg, r, 0.f) + bias[tid], 0.f);
        }
        __syncthreads();
    }
}

// =================== cooperative mega-kernel ===================
struct MegaArgs {
    const float *x, *ea; const int *srcv, *dstv, *batch;
    const float *Wf1,*bf1,*Ws1,*bs1,*Wf2,*bf2,*Ws2,*bs2;
    const float *Wg1,*asrc1,*adst1,*bg1,*Wg2,*asrc2,*adst2,*bg2;
    const float *Wl1,*bl1,*Wl2,*bl2;
    float* out;
    float *XA,*XB,*O1,*O2,*ALs,*ALd;
    bf16 *ABh,*HG1h,*HG2h;
    int *deg,*cur,*rowptr,*esrc,*eord,*bsum,*boff;
};

__global__ __launch_bounds__(256) void k_mega(MegaArgs A){
    cg::grid_group g = cg::this_grid();
    __shared__ MegaLDS L;
    const int tid = threadIdx.x;
    const int gid = blockIdx.x*256 + tid, gsz = gridDim.x*256;
    const int gwid = gid >> 6, gnw = gsz >> 6;

    // P0: zero deg + CGConv1 precompute
    load_sC(L.sC, A.Wf1, A.Ws1);
    __syncthreads();
    for (int i = gid; i < N_NODES; i += gsz) A.deg[i] = 0;
    pre_phase(A.x, A.bf1, A.bs1, L.sC, A.ABh, gid, gsz);
    g.sync();
    // P1: degree histogram
    for (int e = gid; e < N_EDGES; e += gsz) atomicAdd(&A.deg[A.dstv[e]], 1);
    g.sync();
    // P2: per-chunk local scan
    for (int chunk = blockIdx.x; chunk < NBLK_SCAN; chunk += gridDim.x){
        int i = chunk*256 + tid;
        int v = (i < N_NODES) ? A.deg[i] : 0;
        L.scan[tid] = v; __syncthreads();
        #pragma unroll
        for (int st = 1; st < 256; st <<= 1){
            int t = (tid >= st) ? L.scan[tid-st] : 0;
            __syncthreads(); L.scan[tid] += t; __syncthreads();
        }
        if (i < N_NODES) A.rowptr[i] = L.scan[tid] - v;
        if (tid == 255) A.bsum[chunk] = L.scan[255];
        __syncthreads();
    }
    g.sync();
    // P3: scan block sums (block 0)
    if (blockIdx.x == 0){
        int v = (tid < NBLK_SCAN) ? A.bsum[tid] : 0;
        L.scan[tid] = v; __syncthreads();
        #pragma unroll
        for (int st = 1; st < 256; st <<= 1){
            int t = (tid >= st) ? L.scan[tid-st] : 0;
            __syncthreads(); L.scan[tid] += t; __syncthreads();
        }
        if (tid < NBLK_SCAN) A.boff[tid] = L.scan[tid] - v;
    }
    g.sync();
    // P4: add offsets, init cur
    for (int i = gid; i < N_NODES; i += gsz){
        int r = A.rowptr[i] + A.boff[i >> 8];
        A.rowptr[i] = r; A.cur[i] = r;
    }
    if (gid == 0) A.rowptr[N_NODES] = N_EDGES;
    g.sync();
    // P5: scatter
    for (int e = gid; e < N_EDGES; e += gsz){
        int d = A.dstv[e];
        int pos = atomicAdd(&A.cur[d], 1);
        A.esrc[pos] = A.srcv[e];
        A.eord[pos] = e;
    }
    g.sync();
    // P6: CGConv1 gather
    gather_phase(A.x, A.ABh, A.ea, A.rowptr, A.esrc, A.eord, A.Wf1, A.Ws1, A.XA, gwid, gnw);
    g.sync();
    // P7: CGConv2 precompute
    load_sC(L.sC, A.Wf2, A.Ws2);
    __syncthreads();
    pre_phase(A.XA, A.bf2, A.bs2, L.sC, A.ABh, gid, gsz);
    g.sync();
    // P8: CGConv2 gather
    gather_phase(A.XA, A.ABh, A.ea, A.rowptr, A.esrc, A.eord, A.Wf2, A.Ws2, A.XB, gwid, gnw);
    g.sync();
    // P9: GAT1 linear + logits
    for (int i = tid; i < 32*96; i += 256) L.sW[i] = A.Wg1[i];
    __syncthreads();
    linear_al_phase<32,96,32>(A.XB, L.sW, A.asrc1, A.adst1, A.HG1h, A.ALs, A.ALd, gid, gsz);
    g.sync();
    // P10: GAT1 fused softmax+agg
    fused2_phase<32>(A.HG1h, A.rowptr, A.esrc, A.ALs, A.ALd, A.bg1, A.O1, &L);
    g.sync();
    // P11: GAT2 linear + logits
    for (int i = tid; i < 96*48; i += 256) L.sW[i] = A.Wg2[i];
    __syncthreads();
    linear_al_phase<96,48,16>(A.O1, L.sW, A.asrc2, A.adst2, A.HG2h, A.ALs, A.ALd, gid, gsz);
    g.sync();
    // P12: GAT2 fused softmax+agg
    fused2_phase<16>(A.HG2h, A.rowptr, A.esrc, A.ALs, A.ALd, A.bg2, A.O2, &L);
    g.sync();
    // P13: pool + MLP
    for (int gr = blockIdx.x; gr < N_GRAPHS; gr += gridDim.x){
        if (tid < 2){
            int key = gr + tid;
            int lo = 0, hi = N_NODES;
            while (lo < hi){ int mid = (lo+hi) >> 1; if (A.batch[mid] < key) lo = mid+1; else hi = mid; }
            L.pm.range[tid] = lo;
        }
        __syncthreads();
        int lo = L.pm.range[0], hi = L.pm.range[1];
        if (tid < 240){
            int c = tid % 48, r = tid / 48;
            float a = 0.f;
            for (int n = lo + r; n < hi; n += 5) a += A.O2[(size_t)n*48 + c];
            L.pm.red[tid] = a;
        }
        __syncthreads();
        if (tid < 48){
            float a = L.pm.red[tid] + L.pm.red[48+tid] + L.pm.red[96+tid]
                    + L.pm.red[144+tid] + L.pm.red[192+tid];
            L.pm.gm[tid] = a / fmaxf((float)(hi - lo), 1.f);
        }
        __syncthreads();
        if (tid < 16){
            float a = A.bl1[tid];
            #pragma unroll
            for (int k = 0; k < 48; k++) a = fmaf(L.pm.gm[k], A.Wl1[k*16 + tid], a);
            L.pm.g1[tid] = fmaxf(a, 0.f);
        }
        __syncthreads();
        if (tid < 10){
            float a = A.bl2[tid];
            #pragma unroll
            for (int k = 0; k < 16; k++) a = fmaf(L.pm.g1[k], A.Wl2[k*10 + tid], a);
            A.out[gr*10 + tid] = a;
        }
        __syncthreads();
    }
}

// =================== fallback standalone kernels (round-14 path) ===================
__global__ void k_zero_i(int* __restrict__ p, int n){
    int i = blockIdx.x*blockDim.x + threadIdx.x;
    if (i < n) p[i] = 0;
}
__global__ void k_hist(const int* __restrict__ dstv, int* __restrict__ deg){
    int e = blockIdx.x*blockDim.x + threadIdx.x;
    if (e < N_EDGES) atomicAdd(&deg[dstv[e]], 1);
}
__global__ __launch_bounds__(256) void k_scan_local(
    const int* __restrict__ deg, int* __restrict__ rowptr, int* __restrict__ bsum){
    __shared__ int sdata[256];
    int i = blockIdx.x*256 + threadIdx.x;
    int v = (i < N_NODES) ? deg[i] : 0;
    sdata[threadIdx.x] = v;
    __syncthreads();
    #pragma unroll
    for (int st = 1; st < 256; st <<= 1){
        int t = (threadIdx.x >= st) ? sdata[threadIdx.x - st] : 0;
        __syncthreads(); sdata[threadIdx.x] += t; __syncthreads();
    }
    if (i < N_NODES) rowptr[i] = sdata[threadIdx.x] - v;
    if (threadIdx.x == 255) bsum[blockIdx.x] = sdata[255];
}
__global__ __launch_bounds__(256) void k_scan_bsums(
    const int* __restrict__ bsum, int* __restrict__ boff){
    __shared__ int sdata[256];
    int v = (threadIdx.x < NBLK_SCAN) ? bsum[threadIdx.x] : 0;
    sdata[threadIdx.x] = v;
    __syncthreads();
    #pragma unroll
    for (int st = 1; st < 256; st <<= 1){
        int t = (threadIdx.x >= st) ? sdata[threadIdx.x - st] : 0;
        __syncthreads(); sdata[threadIdx.x] += t; __syncthreads();
    }
    if (threadIdx.x < NBLK_SCAN) boff[threadIdx.x] = sdata[threadIdx.x] - v;
}
__global__ void k_scan_add(int* __restrict__ rowptr, const int* __restrict__ boff,
                           int* __restrict__ cur){
    int i = blockIdx.x*blockDim.x + threadIdx.x;
    if (i < N_NODES){
        int r = rowptr[i] + boff[i >> 8];
        rowptr[i] = r; cur[i] = r;
    }
    if (i == 0) rowptr[N_NODES] = N_EDGES;
}
__global__ void k_scatter(const int* __restrict__ srcv, const int* __restrict__ dstv,
                          int* __restrict__ cur, int* __restrict__ esrc,
                          int* __restrict__ eord){
    int e = blockIdx.x*blockDim.x + threadIdx.x;
    if (e >= N_EDGES) return;
    int d = dstv[e];
    int pos = atomicAdd(&cur[d], 1);
    esrc[pos] = srcv[e];
    eord[pos] = e;
}
__global__ __launch_bounds__(256) void k_pre(
    const float* __restrict__ x,
    const float* __restrict__ Wf, const float* __restrict__ bf,
    const float* __restrict__ Ws, const float* __restrict__ bs,
    bf16* __restrict__ AB)
{
    __shared__ float sC[32*128];
    load_sC(sC, Wf, Ws);
    __syncthreads();
    pre_phase(x, bf, bs, sC, AB, blockIdx.x*256 + threadIdx.x, gridDim.x*256);
}
__global__ __launch_bounds__(256) void k_cg_gather(
    const float* __restrict__ xin, const bf16* __restrict__ AB,
    const float* __restrict__ ea,
    const int* __restrict__ rowptr, const int* __restrict__ esrc,
    const int* __restrict__ eord,
    const float* __restrict__ Wf, const float* __restrict__ Ws,
    float* __restrict__ outp)
{
    int gwid = (blockIdx.x*256 + threadIdx.x) >> 6;
    int gnw  = (gridDim.x*256) >> 6;
    gather_phase(xin, AB, ea, rowptr, esrc, eord, Wf, Ws, outp, gwid, gnw);
}
template<int Ci, int Co, int C>
__global__ __launch_bounds__(256) void k_linear_al(
    const float* __restrict__ in, const float* __restrict__ W,
    const float* __restrict__ a_src, const float* __restrict__ a_dst,
    bf16* __restrict__ out, float* __restrict__ als, float* __restrict__ ald)
{
    __shared__ float sW[Ci*Co];
    for (int i = threadIdx.x; i < Ci*Co; i += 256) sW[i] = W[i];
    __syncthreads();
    linear_al_phase<Ci,Co,C>(in, sW, a_src, a_dst, out, als, ald,
                             blockIdx.x*256 + threadIdx.x, gridDim.x*256);
}
template<int C>
__global__ __launch_bounds__(256) void k_gat_fused2(
    const bf16* __restrict__ hg, const int* __restrict__ rowptr,
    const int* __restrict__ esrc,
    const float* __restrict__ als, const float* __restrict__ ald,
    const float* __restrict__ bias, float* __restrict__ O)
{
    __shared__ MegaLDS L;
    fused2_phase<C>(hg, rowptr, esrc, als, ald, bias, O, &L);
}
__global__ __launch_bounds__(256) void k_pool_mlp(
    const float* __restrict__ O2, const int* __restrict__ batch,
    const float* __restrict__ Wl1, const float* __restrict__ bl1,
    const float* __restrict__ Wl2, const float* __restrict__ bl2,
    float* __restrict__ out){
    __shared__ int s_range[2];
    __shared__ float red[240];
    __shared__ float gm[48];
    __shared__ float g1[16];
    const int gr = blockIdx.x;
    const int tid = threadIdx.x;
    if (tid < 2){
        int key = gr + tid;
        int lo = 0, hi = N_NODES;
        while (lo < hi){ int mid = (lo+hi) >> 1; if (batch[mid] < key) lo = mid+1; else hi = mid; }
        s_range[tid] = lo;
    }
    __syncthreads();
    const int lo = s_range[0], hi = s_range[1];
    if (tid < 240){
        const int c = tid % 48, r = tid / 48;
        float a = 0.f;
        for (int n = lo + r; n < hi; n += 5) a += O2[(size_t)n*48 + c];
        red[tid] = a;
    }
    __syncthreads();
    if (tid < 48){
        float a = red[tid] + red[48+tid] + red[96+tid] + red[144+tid] + red[192+tid];
        gm[tid] = a / fmaxf((float)(hi - lo), 1.f);
    }
    __syncthreads();
    if (tid < 16){
        float a = bl1[tid];
        #pragma unroll
        for (int k = 0; k < 48; k++) a = fmaf(gm[k], Wl1[k*16 + tid], a);
        g1[tid] = fmaxf(a, 0.f);
    }
    __syncthreads();
    if (tid < 10){
        float a = bl2[tid];
        #pragma unroll
        for (int k = 0; k < 16; k++) a = fmaf(g1[k], Wl2[k*10 + tid], a);
        out[gr*10 + tid] = a;
    }
}

extern "C" void kernel_launch(void* const* d_in, const int* in_sizes, int n_in,
                              void* d_out, int out_size, void* d_ws, size_t ws_size,
                              hipStream_t stream) {
    const float* x    = (const float*)d_in[0];
    const float* ea   = (const float*)d_in[1];
    const int*   ei   = (const int*)  d_in[2];
    const int*   batch= (const int*)  d_in[3];
    const float* Wf1 = (const float*)d_in[4];  const float* bf1 = (const float*)d_in[5];
    const float* Ws1 = (const float*)d_in[6];  const float* bs1 = (const float*)d_in[7];
    const float* Wf2 = (const float*)d_in[8];  const float* bf2 = (const float*)d_in[9];
    const float* Ws2 = (const float*)d_in[10]; const float* bs2 = (const float*)d_in[11];
    const float* Wg1 = (const float*)d_in[12];
    const float* asrc1=(const float*)d_in[13]; const float* adst1=(const float*)d_in[14];
    const float* bg1 = (const float*)d_in[15];
    const float* Wg2 = (const float*)d_in[16];
    const float* asrc2=(const float*)d_in[17]; const float* adst2=(const float*)d_in[18];
    const float* bg2 = (const float*)d_in[19];
    const float* Wl1 = (const float*)d_in[20]; const float* bl1 = (const float*)d_in[21];
    const float* Wl2 = (const float*)d_in[22]; const float* bl2 = (const float*)d_in[23];
    float* out = (float*)d_out;

    const int* srcv = ei;
    const int* dstv = ei + N_EDGES;

    // ---- workspace arena (float units; lifetime overlays; ~62 MB) ----
    float* w   = (float*)d_ws;
    float* XA  = w;                  // 1.6M relu(conv1)
    float* XB  = XA + 1600000;       // 1.6M relu(conv2) = GAT1 input
    float* R2  = XB + 1600000;       // 6.4M floats: ABh/HG1h/HG2h (bf16) + O2
    float* R3  = R2 + 6400000;       // 4.8M O1 (GAT phase)
    float* ALs = R3 + 4800000;       // 150k
    float* ALd = ALs + 150000;       // 150k
    float* GM  = ALd + 150000;       // 3072 (scratch)
    int* deg    = (int*)(GM + 3072); // 50k
    int* cur    = deg + 50000;       // 50k
    int* rowptr = cur + 50000;       // 50004
    int* esrc   = rowptr + 50004;    // 800k
    int* eord   = esrc + 800000;     // 800k
    int* bsum   = eord + 800000;     // 196
    int* boff   = bsum + NBLK_SCAN;  // 196
    bf16* ABh   = (bf16*)R2;         // conv phase
    bf16* HG1h  = (bf16*)R2;         // GAT1
    bf16* HG2h  = (bf16*)R2;         // GAT2
    float* O2   = R2 + 2400000;      // disjoint from HG2h span
    float* O1   = R3;                // GAT phase
    (void)ws_size; (void)in_sizes; (void)n_in; (void)out_size;

    // ---- try cooperative mega-kernel path ----
    int dev = 0; hipGetDevice(&dev);
    int coop = 0; hipDeviceGetAttribute(&coop, hipDeviceAttributeCooperativeLaunch, dev);
    int nCU = 0;  hipDeviceGetAttribute(&nCU, hipDeviceAttributeMultiprocessorCount, dev);
    int nb = 0;
    hipOccupancyMaxActiveBlocksPerMultiprocessor(&nb, k_mega, 256, 0);
    int grid = nb * nCU;
    if (grid > 2048) grid = 2048;
    if (coop && grid >= 256){
        MegaArgs A;
        A.x=x; A.ea=ea; A.srcv=srcv; A.dstv=dstv; A.batch=batch;
        A.Wf1=Wf1; A.bf1=bf1; A.Ws1=Ws1; A.bs1=bs1;
        A.Wf2=Wf2; A.bf2=bf2; A.Ws2=Ws2; A.bs2=bs2;
        A.Wg1=Wg1; A.asrc1=asrc1; A.adst1=adst1; A.bg1=bg1;
        A.Wg2=Wg2; A.asrc2=asrc2; A.adst2=adst2; A.bg2=bg2;
        A.Wl1=Wl1; A.bl1=bl1; A.Wl2=Wl2; A.bl2=bl2; A.out=out;
        A.XA=XA; A.XB=XB; A.O1=O1; A.O2=O2; A.ALs=ALs; A.ALd=ALd;
        A.ABh=ABh; A.HG1h=HG1h; A.HG2h=HG2h;
        A.deg=deg; A.cur=cur; A.rowptr=rowptr; A.esrc=esrc; A.eord=eord;
        A.bsum=bsum; A.boff=boff;
        void* kargs[] = { (void*)&A };
        hipError_t err = hipLaunchCooperativeKernel(k_mega, dim3(grid), dim3(256),
                                                    kargs, 0, stream);
        if (err == hipSuccess) return;
    }

    // ---- fallback: proven 14-kernel path ----
    auto G = [](int n){ return (n + 255)/256; };
    k_zero_i<<<G(N_NODES), 256, 0, stream>>>(deg, N_NODES);
    k_hist<<<G(N_EDGES), 256, 0, stream>>>(dstv, deg);
    k_scan_local<<<NBLK_SCAN, 256, 0, stream>>>(deg, rowptr, bsum);
    k_scan_bsums<<<1, 256, 0, stream>>>(bsum, boff);
    k_scan_add<<<G(N_NODES), 256, 0, stream>>>(rowptr, boff, cur);
    k_scatter<<<G(N_EDGES), 256, 0, stream>>>(srcv, dstv, cur, esrc, eord);
    k_pre<<<1280, 256, 0, stream>>>(x, Wf1, bf1, Ws1, bs1, ABh);
    k_cg_gather<<<(N_NODES*64)/256, 256, 0, stream>>>(x, ABh, ea, rowptr, esrc, eord, Wf1, Ws1, XA);
    k_pre<<<1280, 256, 0, stream>>>(XA, Wf2, bf2, Ws2, bs2, ABh);
    k_cg_gather<<<(N_NODES*64)/256, 256, 0, stream>>>(XA, ABh, ea, rowptr, esrc, eord, Wf2, Ws2, XB);
    k_linear_al<32,96,32><<<1280, 256, 0, stream>>>(XB, Wg1, asrc1, adst1, HG1h, ALs, ALd);
    k_gat_fused2<32><<<N_NODES, 256, 0, stream>>>(HG1h, rowptr, esrc, ALs, ALd, bg1, O1);
    k_linear_al<96,48,16><<<1280, 256, 0, stream>>>(O1, Wg2, asrc2, adst2, HG2h, ALs, ALd);
    k_gat_fused2<16><<<N_NODES, 256, 0, stream>>>(HG2h, rowptr, esrc, ALs, ALd, bg2, O2);
    k_pool_mlp<<<N_GRAPHS, 256, 0, stream>>>(O2, batch, Wl1, bl1, Wl2, bl2, out);
}

// Round 16
// 587.304 us; speedup vs baseline: 4.5109x; 4.5109x over previous
//
#include <hip/hip_runtime.h>
#include <hip/hip_bf16.h>
#include <math.h>

#define N_NODES 50000
#define N_EDGES 800000
#define IN_FEAT 32
#define EDGE_FEAT 8
#define HEADS 3
#define N_GRAPHS 64
#define NBLK_SCAN 196   // ceil(50000/256)

typedef __hip_bfloat16 bf16;

static __device__ __forceinline__ float fast_sigmoid(float x){
    return __builtin_amdgcn_rcpf(1.f + __expf(-x));
}
static __device__ __forceinline__ float fast_softplus(float x){
    return fmaxf(x, 0.f) + __logf(1.f + __expf(-fabsf(x)));
}
static __device__ __forceinline__ float lrelu02(float x){ return x > 0.f ? x : 0.2f*x; }
static __device__ __forceinline__ float b2f(bf16 h){ return __bfloat162float(h); }

// ---------------- CSR build ----------------
__global__ void k_hist(const int* __restrict__ dstv, int* __restrict__ deg){
    int e = blockIdx.x*blockDim.x + threadIdx.x;
    if (e < N_EDGES) atomicAdd(&deg[dstv[e]], 1);
}
// ONE-kernel scan: block b computes its global offset by redundantly summing
// deg[0..256b) (L2-hot, ~20 MB total across 196 blocks), then local LDS scan.
__global__ __launch_bounds__(256) void k_scan1(
    const int* __restrict__ deg, int* __restrict__ rowptr, int* __restrict__ cur){
    __shared__ int sdata[256];
    __shared__ int s_off;
    const int tid = threadIdx.x;
    const int lim = blockIdx.x*256;
    // global offset = sum deg[0..lim)
    int part = 0;
    for (int i = tid; i < lim; i += 256) part += deg[i];
    sdata[tid] = part;
    __syncthreads();
    #pragma unroll
    for (int st = 128; st; st >>= 1){
        if (tid < st) sdata[tid] += sdata[tid + st];
        __syncthreads();
    }
    if (tid == 0) s_off = sdata[0];
    __syncthreads();
    const int off = s_off;
    __syncthreads();
    // local inclusive scan of this chunk
    int i = lim + tid;
    int v = (i < N_NODES) ? deg[i] : 0;
    sdata[tid] = v;
    __syncthreads();
    #pragma unroll
    for (int st = 1; st < 256; st <<= 1){
        int t = (tid >= st) ? sdata[tid - st] : 0;
        __syncthreads();
        sdata[tid] += t;
        __syncthreads();
    }
    if (i < N_NODES){
        int r = off + sdata[tid] - v;
        rowptr[i] = r; cur[i] = r;
    }
    if (blockIdx.x == 0 && tid == 0) rowptr[N_NODES] = N_EDGES;
}
__global__ void k_scatter(const int* __restrict__ srcv, const int* __restrict__ dstv,
                          int* __restrict__ cur, int* __restrict__ esrc,
                          int* __restrict__ eord){
    int e = blockIdx.x*blockDim.x + threadIdx.x;
    if (e >= N_EDGES) return;
    int d = dstv[e];
    int pos = atomicAdd(&cur[d], 1);
    esrc[pos] = srcv[e];
    eord[pos] = e;
}

// ---------------- CGConv ----------------
// PERSISTENT; column order [AF | AS | BF | BS]; optionally zeroes deg first
// (merges the k_zero dispatch into the conv1 precompute).
__global__ __launch_bounds__(256) void k_pre(
    const float* __restrict__ x,
    const float* __restrict__ Wf, const float* __restrict__ bf,
    const float* __restrict__ Ws, const float* __restrict__ bs,
    bf16* __restrict__ AB, int* __restrict__ deg_zero)
{
    __shared__ float sC[32*128];
    for (int i = threadIdx.x; i < 32*128; i += 256){
        int k = i >> 7, j = i & 127;
        float w;
        if      (j < 32)  w = Wf[k*32 + j];             // AF
        else if (j < 64)  w = Ws[k*32 + (j-32)];        // AS
        else if (j < 96)  w = Wf[(32+k)*32 + (j-64)];   // BF
        else              w = Ws[(32+k)*32 + (j-96)];   // BS
        sC[i] = w;
    }
    __syncthreads();
    const int gid = blockIdx.x*256 + threadIdx.x, gsz = gridDim.x*256;
    if (deg_zero){
        for (int i = gid; i < N_NODES; i += gsz) deg_zero[i] = 0;
    }
    for (int idx = gid; idx < N_NODES*128; idx += gsz){
        int n = idx >> 7, j = idx & 127;
        float a = 0.f;
        if (j < 32) a = bf[j];
        else if (j < 64) a = bs[j-32];
        const float4* xr = (const float4*)(x + (size_t)n*32);
        #pragma unroll
        for (int k4 = 0; k4 < 8; k4++){
            float4 v = xr[k4];
            int k = k4*4;
            a = fmaf(v.x, sC[(k  )*128 + j], a);
            a = fmaf(v.y, sC[(k+1)*128 + j], a);
            a = fmaf(v.z, sC[(k+2)*128 + j], a);
            a = fmaf(v.w, sC[(k+3)*128 + j], a);
        }
        AB[idx] = __float2bfloat16(a);
    }
}

// wave-per-node gather; scalarized CSR walk + edge pairing; one 128B line per
// edge gather; 8-edge unroll (round-14 verbatim).
__global__ __launch_bounds__(256) void k_cg_gather(
    const float* __restrict__ xin, const bf16* __restrict__ AB,
    const float* __restrict__ ea,
    const int* __restrict__ rowptr, const int* __restrict__ esrc,
    const int* __restrict__ eord,
    const float* __restrict__ Wf, const float* __restrict__ Ws,
    float* __restrict__ outp)
{
    const int lane = threadIdx.x & 63;
    const int half = lane >> 5, c = lane & 31;
    const float* WzOwn  = half ? Ws : Wf;
    const float* WzSwap = half ? Wf : Ws;
    float wo[8], wx[8];
    #pragma unroll
    for (int k = 0; k < 8; k++){
        wo[k] = WzOwn[(64+k)*32+c];
        wx[k] = WzSwap[(64+k)*32+c];
    }
    const int d = __builtin_amdgcn_readfirstlane((blockIdx.x*256 + threadIdx.x) >> 6);
    if (d >= N_NODES) return;
    const int lo = rowptr[d], hi = rowptr[d+1];
    const int offOwn  = 64 + half*32 + c;        // BF / BS
    const int offSwap = 96 - half*32 + c;        // BS / BF
    const float baseOwn  = b2f(AB[d*128 + half*32 + c]);          // AF / AS
    const float baseSwap = b2f(AB[d*128 + (32 - half*32) + c]);   // AS / AF
    float acc = 0.f;

    auto mv = [&](float v, const float* w8, const float4& e0, const float4& e1) -> float {
        v = fmaf(e0.x, w8[0], v); v = fmaf(e0.y, w8[1], v);
        v = fmaf(e0.z, w8[2], v); v = fmaf(e0.w, w8[3], v);
        v = fmaf(e1.x, w8[4], v); v = fmaf(e1.y, w8[5], v);
        v = fmaf(e1.z, w8[6], v); v = fmaf(e1.w, w8[7], v);
        return v;
    };
    auto pair = [&](int i) -> float {
        int sA = __builtin_amdgcn_readfirstlane(esrc[i]);
        int sB = __builtin_amdgcn_readfirstlane(esrc[i+1]);
        int eA = __builtin_amdgcn_readfirstlane(eord[i]);
        int eB = __builtin_amdgcn_readfirstlane(eord[i+1]);
        float bA = b2f(AB[sA*128 + offOwn]);
        float bB = b2f(AB[sB*128 + offSwap]);
        const float4* epA = (const float4*)(ea + (size_t)eA*8);
        const float4* epB = (const float4*)(ea + (size_t)eB*8);
        float4 ea0 = epA[0], ea1 = epA[1];
        float4 ea2 = epB[0], ea3 = epB[1];
        float vA = mv(baseOwn  + bA, wo, ea0, ea1);
        float vB = mv(baseSwap + bB, wx, ea2, ea3);
        float xA = __shfl_xor(vA, 32, 64);
        float xB = __shfl_xor(vB, 32, 64);
        float fv = half ? vB : vA;
        float sv = half ? xB : xA;
        return fast_sigmoid(fv) * fast_softplus(sv);
    };

    int i = lo;
    for (; i + 7 < hi; i += 8){
        acc += pair(i);   acc += pair(i+2);
        acc += pair(i+4); acc += pair(i+6);
    }
    for (; i + 1 < hi; i += 2)
        acc += pair(i);
    for (; i < hi; i++){
        int s = __builtin_amdgcn_readfirstlane(esrc[i]);
        int e = __builtin_amdgcn_readfirstlane(eord[i]);
        float b = b2f(AB[s*128 + offOwn]);
        const float4* ep = (const float4*)(ea + (size_t)e*8);
        float4 ea0 = ep[0], ea1 = ep[1];
        float v = mv(baseOwn + b, wo, ea0, ea1);
        float o = __shfl_xor(v, 32, 64);
        if (half == 0) acc += fast_sigmoid(v) * fast_softplus(o);
    }
    float total = acc + __shfl_xor(acc, 32, 64);
    if (half == 0) outp[d*32 + c] = fmaxf(xin[d*32 + c] + total, 0.f);
}

// ---------------- GAT ----------------
// PERSISTENT linear + fused logits (shfl reductions) — round-14 verbatim.
template<int Ci, int Co, int NN>
__global__ __launch_bounds__(NN*Co) void k_linear_al(
    const float* __restrict__ in, const float* __restrict__ W,
    const float* __restrict__ a_src, const float* __restrict__ a_dst,
    bf16* __restrict__ out, float* __restrict__ als, float* __restrict__ ald,
    int N)
{
    const int C = Co / HEADS;
    __shared__ float sW[Ci*Co];
    for (int i = threadIdx.x; i < Ci*Co; i += NN*Co) sW[i] = W[i];
    __syncthreads();
    const int tid = threadIdx.x;
    const int nl = tid / Co, co = tid % Co;
    const float asw = a_src[co], adw = a_dst[co];
    for (int n0 = blockIdx.x*NN; n0 < N; n0 += gridDim.x*NN){
        const int n = n0 + nl;
        float a = 0.f;
        if (n < N){
            const float* row = in + (size_t)n*Ci;
            #pragma unroll
            for (int k = 0; k < Ci; k++) a = fmaf(row[k], sW[k*Co + co], a);
            out[(size_t)n*Co + co] = __float2bfloat16(a);
        }
        float s1 = a*asw, s2 = a*adw;
        #pragma unroll
        for (int off = C/2; off; off >>= 1){
            s1 += __shfl_xor(s1, off, 64);
            s2 += __shfl_xor(s2, off, 64);
        }
        if ((co & (C-1)) == 0 && n < N){
            als[n*HEADS + co/C] = s1;
            ald[n*HEADS + co/C] = s2;
        }
    }
}

// FUSED softmax+aggregation without max pass; agg unrolled x8 (round-14 verbatim).
template<int C, int BLK>
__global__ __launch_bounds__(BLK) void k_gat_fused2(
    const bf16* __restrict__ hg, const int* __restrict__ rowptr,
    const int* __restrict__ esrc,
    const float* __restrict__ als, const float* __restrict__ ald,
    const float* __restrict__ bias, float* __restrict__ O)
{
    const int HC = HEADS*C;
    const int CH = 128;
    __shared__ float p0b[128], p1b[128], p2b[128];
    __shared__ float sred[3];
    const int d = blockIdx.x;
    const int tid = threadIdx.x;
    const int lo = rowptr[d], hi = rowptr[d+1];
    const float ad0 = ald[d*3+0], ad1 = ald[d*3+1], ad2 = ald[d*3+2];
    const int h = (tid < HC) ? tid / C : 0;
    const float* ph = (h == 0) ? p0b : (h == 1) ? p1b : p2b;
    float acc = 0.f;
    float ps0 = 0.f, ps1 = 0.f, ps2 = 0.f;
    for (int base = lo; base < hi; base += CH){
        int cnt = min(CH, hi - base);
        if (tid < 64){
            for (int j = tid; j < cnt; j += 64){
                int s = esrc[base + j];
                float p0 = __expf(lrelu02(als[s*3+0] + ad0));
                float p1 = __expf(lrelu02(als[s*3+1] + ad1));
                float p2 = __expf(lrelu02(als[s*3+2] + ad2));
                p0b[j] = p0; p1b[j] = p1; p2b[j] = p2;
                ps0 += p0; ps1 += p1; ps2 += p2;
            }
        }
        __syncthreads();
        if (tid < HC){
            int j = 0;
            for (; j + 7 < cnt; j += 8){
                int i = base + j;
                int s0 = __builtin_amdgcn_readfirstlane(esrc[i]);
                int s1 = __builtin_amdgcn_readfirstlane(esrc[i+1]);
                int s2 = __builtin_amdgcn_readfirstlane(esrc[i+2]);
                int s3 = __builtin_amdgcn_readfirstlane(esrc[i+3]);
                int s4 = __builtin_amdgcn_readfirstlane(esrc[i+4]);
                int s5 = __builtin_amdgcn_readfirstlane(esrc[i+5]);
                int s6 = __builtin_amdgcn_readfirstlane(esrc[i+6]);
                int s7 = __builtin_amdgcn_readfirstlane(esrc[i+7]);
                float g0 = b2f(hg[s0*HC + tid]);
                float g1 = b2f(hg[s1*HC + tid]);
                float g2 = b2f(hg[s2*HC + tid]);
                float g3 = b2f(hg[s3*HC + tid]);
                float g4 = b2f(hg[s4*HC + tid]);
                float g5 = b2f(hg[s5*HC + tid]);
                float g6 = b2f(hg[s6*HC + tid]);
                float g7 = b2f(hg[s7*HC + tid]);
                acc = fmaf(ph[j],   g0, acc);
                acc = fmaf(ph[j+1], g1, acc);
                acc = fmaf(ph[j+2], g2, acc);
                acc = fmaf(ph[j+3], g3, acc);
                acc = fmaf(ph[j+4], g4, acc);
                acc = fmaf(ph[j+5], g5, acc);
                acc = fmaf(ph[j+6], g6, acc);
                acc = fmaf(ph[j+7], g7, acc);
            }
            for (; j + 3 < cnt; j += 4){
                int i = base + j;
                int s0 = __builtin_amdgcn_readfirstlane(esrc[i]);
                int s1 = __builtin_amdgcn_readfirstlane(esrc[i+1]);
                int s2 = __builtin_amdgcn_readfirstlane(esrc[i+2]);
                int s3 = __builtin_amdgcn_readfirstlane(esrc[i+3]);
                float g0 = b2f(hg[s0*HC + tid]);
                float g1 = b2f(hg[s1*HC + tid]);
                float g2 = b2f(hg[s2*HC + tid]);
                float g3 = b2f(hg[s3*HC + tid]);
                acc = fmaf(ph[j],   g0, acc);
                acc = fmaf(ph[j+1], g1, acc);
                acc = fmaf(ph[j+2], g2, acc);
                acc = fmaf(ph[j+3], g3, acc);
            }
            for (; j < cnt; j++){
                int s = __builtin_amdgcn_readfirstlane(esrc[base + j]);
                acc = fmaf(ph[j], b2f(hg[s*HC + tid]), acc);
            }
        }
        __syncthreads();
    }
    if (tid < 64){
        #pragma unroll
        for (int off = 32; off; off >>= 1){
            ps0 += __shfl_xor(ps0, off, 64);
            ps1 += __shfl_xor(ps1, off, 64);
            ps2 += __shfl_xor(ps2, off, 64);
        }
        if (tid == 0){ sred[0] = ps0; sred[1] = ps1; sred[2] = ps2; }
    }
    __syncthreads();
    if (tid < HC){
        float slh = lrelu02(als[d*3+h] + ald[d*3+h]);
        float p_self = __expf(slh);
        float r = __builtin_amdgcn_rcpf(sred[h] + p_self + 1e-16f);
        float self_hg = b2f(hg[d*HC + tid]);
        O[d*HC + tid] = fmaxf(fmaf(acc + p_self*self_hg, r, 0.f) + bias[tid], 0.f);
    }
}

// ---------------- pool + MLP (fused) ----------------
__global__ __launch_bounds__(256) void k_pool_mlp(
    const float* __restrict__ O2, const int* __restrict__ batch,
    const float* __restrict__ Wl1, const float* __restrict__ bl1,
    const float* __restrict__ Wl2, const float* __restrict__ bl2,
    float* __restrict__ out){
    __shared__ int s_range[2];
    __shared__ float red[240];
    __shared__ float gm[48];
    __shared__ float g1[16];
    const int gr = blockIdx.x;
    const int tid = threadIdx.x;
    if (tid < 2){
        int key = gr + tid;
        int lo = 0, hi = N_NODES;
        while (lo < hi){ int mid = (lo+hi) >> 1; if (batch[mid] < key) lo = mid+1; else hi = mid; }
        s_range[tid] = lo;
    }
    __syncthreads();
    const int lo = s_range[0], hi = s_range[1];
    if (tid < 240){
        const int c = tid % 48, r = tid / 48;
        float a = 0.f;
        for (int n = lo + r; n < hi; n += 5) a += O2[(size_t)n*48 + c];
        red[tid] = a;
    }
    __syncthreads();
    if (tid < 48){
        float a = red[tid] + red[48+tid] + red[96+tid] + red[144+tid] + red[192+tid];
        gm[tid] = a / fmaxf((float)(hi - lo), 1.f);
    }
    __syncthreads();
    if (tid < 16){
        float a = bl1[tid];
        #pragma unroll
        for (int k = 0; k < 48; k++) a = fmaf(gm[k], Wl1[k*16 + tid], a);
        g1[tid] = fmaxf(a, 0.f);
    }
    __syncthreads();
    if (tid < 10){
        float a = bl2[tid];
        #pragma unroll
        for (int k = 0; k < 16; k++) a = fmaf(g1[k], Wl2[k*10 + tid], a);
        out[gr*10 + tid] = a;
    }
}

extern "C" void kernel_launch(void* const* d_in, const int* in_sizes, int n_in,
                              void* d_out, int out_size, void* d_ws, size_t ws_size,
                              hipStream_t stream) {
    const float* x    = (const float*)d_in[0];
    const float* ea   = (const float*)d_in[1];
    const int*   ei   = (const int*)  d_in[2];
    const int*   batch= (const int*)  d_in[3];
    const float* Wf1 = (const float*)d_in[4];  const float* bf1 = (const float*)d_in[5];
    const float* Ws1 = (const float*)d_in[6];  const float* bs1 = (const float*)d_in[7];
    const float* Wf2 = (const float*)d_in[8];  const float* bf2 = (const float*)d_in[9];
    const float* Ws2 = (const float*)d_in[10]; const float* bs2 = (const float*)d_in[11];
    const float* Wg1 = (const float*)d_in[12];
    const float* asrc1=(const float*)d_in[13]; const float* adst1=(const float*)d_in[14];
    const float* bg1 = (const float*)d_in[15];
    const float* Wg2 = (const float*)d_in[16];
    const float* asrc2=(const float*)d_in[17]; const float* adst2=(const float*)d_in[18];
    const float* bg2 = (const float*)d_in[19];
    const float* Wl1 = (const float*)d_in[20]; const float* bl1 = (const float*)d_in[21];
    const float* Wl2 = (const float*)d_in[22]; const float* bl2 = (const float*)d_in[23];
    float* out = (float*)d_out;

    const int* srcv = ei;
    const int* dstv = ei + N_EDGES;

    // ---- workspace arena (float units; lifetime overlays; ~62 MB) ----
    float* w   = (float*)d_ws;
    float* XA  = w;                  // 1.6M relu(conv1)
    float* XB  = XA + 1600000;       // 1.6M relu(conv2) = GAT1 input
    float* R2  = XB + 1600000;       // 6.4M floats: ABh/HG1h/HG2h (bf16) + O2
    float* R3  = R2 + 6400000;       // 4.8M O1 (GAT phase)
    float* ALs = R3 + 4800000;       // 150k
    float* ALd = ALs + 150000;       // 150k
    float* GM  = ALd + 150000;       // 3072 (scratch)
    int* deg    = (int*)(GM + 3072); // 50k
    int* cur    = deg + 50000;       // 50k
    int* rowptr = cur + 50000;       // 50004
    int* esrc   = rowptr + 50004;    // 800k
    int* eord   = esrc + 800000;     // 800k
    bf16* ABh   = (bf16*)R2;         // conv phase
    bf16* HG1h  = (bf16*)R2;         // GAT1
    bf16* HG2h  = (bf16*)R2;         // GAT2
    float* O2   = R2 + 2400000;      // disjoint from HG2h span
    float* O1   = R3;                // GAT phase
    (void)ws_size; (void)in_sizes; (void)n_in; (void)out_size;

    auto G = [](int n){ return (n + 255)/256; };

    // 12 dispatches total (was 15): zero merged into pre1; 3-kernel scan -> 1.
    // K1: deg zero + CGConv1 precompute
    k_pre<<<1280, 256, 0, stream>>>(x, Wf1, bf1, Ws1, bs1, ABh, deg);
    // K2: degree histogram
    k_hist<<<G(N_EDGES), 256, 0, stream>>>(dstv, deg);
    // K3: one-kernel scan (redundant-offset trick)
    k_scan1<<<NBLK_SCAN, 256, 0, stream>>>(deg, rowptr, cur);
    // K4: scatter
    k_scatter<<<G(N_EDGES), 256, 0, stream>>>(srcv, dstv, cur, esrc, eord);
    // K5: CGConv1 gather
    k_cg_gather<<<(N_NODES*64)/256, 256, 0, stream>>>(x, ABh, ea, rowptr, esrc, eord, Wf1, Ws1, XA);
    // K6: CGConv2 precompute
    k_pre<<<1280, 256, 0, stream>>>(XA, Wf2, bf2, Ws2, bs2, ABh, nullptr);
    // K7: CGConv2 gather
    k_cg_gather<<<(N_NODES*64)/256, 256, 0, stream>>>(XA, ABh, ea, rowptr, esrc, eord, Wf2, Ws2, XB);
    // K8: GAT1 linear + logits
    k_linear_al<32,96,2><<<1280, 192, 0, stream>>>(XB, Wg1, asrc1, adst1, HG1h, ALs, ALd, N_NODES);
    // K9: GAT1 fused softmax+agg
    k_gat_fused2<32,128><<<N_NODES, 128, 0, stream>>>(HG1h, rowptr, esrc, ALs, ALd, bg1, O1);
    // K10: GAT2 linear + logits
    k_linear_al<96,48,4><<<1280, 192, 0, stream>>>(O1, Wg2, asrc2, adst2, HG2h, ALs, ALd, N_NODES);
    // K11: GAT2 fused softmax+agg
    k_gat_fused2<16,64><<<N_NODES, 64, 0, stream>>>(HG2h, rowptr, esrc, ALs, ALd, bg2, O2);
    // K12: pool + MLP
    k_pool_mlp<<<N_GRAPHS, 256, 0, stream>>>(O2, batch, Wl1, bl1, Wl2, bl2, out);
}